// Round 5
// baseline (125.962 us; speedup 1.0000x reference)
//
#include <hip/hip_runtime.h>
#include <cstddef>
#include <cstdint>

#define FN_ 100000
#define V_  50000
#define B_  8
#define NT  256
#define NBX ((FN_ + NT - 1) / NT)   // 391; last block: 160 valid cols

// d_ws layout (bytes): 48 weight tiles of 1 KB (fragment order), then shs f32[448]
//   tiles  0..15 : combined L1 weights (256x32): rows 0-63 c1, 64-127 e0, 128-191 e1, 192-255 e2
//   tiles 16..23 : c2 (64x64)   tile = 16 + 2*rt + s
//   tiles 24..31 : v2 (64x64, x1/3 folded)  tile = 24 + 2*rt + s
//   tiles 32..47 : s  (64x128)  tile = 32 + 4*rt + s
#define WS_SHS 49152

typedef _Float16 f16;
typedef f16   f16x8 __attribute__((ext_vector_type(8)));
typedef float f32x4 __attribute__((ext_vector_type(4)));

struct Ptrs { const void* p[33]; };

union Pk2 { f16 h[2]; uint32_t u; };
union Pk4 { f16 h[4]; uint2 u; };
union Pk8 { f16 h[8]; uint4 u; };

// ---------------- prep: fold BN into f16 weights, fragment-ordered (validated) ----------------
__global__ __launch_bounds__(1024) void sd_prep(Ptrs in, f16* __restrict__ wsW,
                                                float* __restrict__ shsG)
{
  const float* __restrict__ cw1 = (const float*)in.p[3];
  const float* __restrict__ cb1 = (const float*)in.p[4];
  const float* __restrict__ c1g = (const float*)in.p[5];
  const float* __restrict__ c1bt= (const float*)in.p[6];
  const float* __restrict__ c1m = (const float*)in.p[7];
  const float* __restrict__ c1v = (const float*)in.p[8];
  const float* __restrict__ cw2 = (const float*)in.p[9];
  const float* __restrict__ cb2 = (const float*)in.p[10];
  const float* __restrict__ c2g = (const float*)in.p[11];
  const float* __restrict__ c2bt= (const float*)in.p[12];
  const float* __restrict__ c2m = (const float*)in.p[13];
  const float* __restrict__ c2v = (const float*)in.p[14];
  const float* __restrict__ vw1 = (const float*)in.p[15];
  const float* __restrict__ vb1 = (const float*)in.p[16];
  const float* __restrict__ v1g = (const float*)in.p[17];
  const float* __restrict__ v1bt= (const float*)in.p[18];
  const float* __restrict__ v1m = (const float*)in.p[19];
  const float* __restrict__ v1v = (const float*)in.p[20];
  const float* __restrict__ vw2 = (const float*)in.p[21];
  const float* __restrict__ vb2 = (const float*)in.p[22];
  const float* __restrict__ v2g = (const float*)in.p[23];
  const float* __restrict__ v2bt= (const float*)in.p[24];
  const float* __restrict__ v2m = (const float*)in.p[25];
  const float* __restrict__ v2v = (const float*)in.p[26];
  const float* __restrict__ sw  = (const float*)in.p[27];
  const float* __restrict__ sb  = (const float*)in.p[28];
  const float* __restrict__ s1g = (const float*)in.p[29];
  const float* __restrict__ s1bt= (const float*)in.p[30];
  const float* __restrict__ s1m = (const float*)in.p[31];
  const float* __restrict__ s1v = (const float*)in.p[32];

  __shared__ float scsL[448];
  const int tid = threadIdx.x;

  if (tid < 448) {
    const float *g, *v, *bb, *m, *bt; int o; float mul = 1.f;
    if (tid < 64)       { o = tid;      g=c1g; v=c1v; bb=cb1; m=c1m; bt=c1bt; }
    else if (tid < 256) { o = tid & 63; g=v1g; v=v1v; bb=vb1; m=v1m; bt=v1bt; }
    else if (tid < 320) { o = tid-256;  g=c2g; v=c2v; bb=cb2; m=c2m; bt=c2bt; }
    else if (tid < 384) { o = tid-320;  g=v2g; v=v2v; bb=vb2; m=v2m; bt=v2bt; mul = 1.f/3.f; }
    else                { o = tid-384;  g=s1g; v=s1v; bb=sb;  m=s1m; bt=s1bt; }
    float s = g[o] * rsqrtf(v[o] + 1e-5f);
    scsL[tid] = s * mul;
    shsG[tid] = ((bb[o] - m[o]) * s + bt[o]) * mul;
  }
  __syncthreads();

  for (int u = tid; u < 3072; u += 1024) {
    const int t = u >> 6, l = u & 63, r15 = l & 15, g4 = l >> 4;
    Pk8 pk;
    if (t < 16) {                                   // L1 combined 256x32
      const int wm = t >> 2, tr = t & 3, row = 64*wm + 16*tr + r15;
#pragma unroll
      for (int j = 0; j < 8; ++j) {
        const int k = 8*g4 + j; float val = 0.f;
        if (wm == 0) { if (k >= 9 && k < 12) val = cw1[row*3 + (k-9)]; }
        else if (k < 9) {
          const int e = wm - 1, o = row - 64*wm, c = (k - 3*e + 9) % 9;
          if (c < 6) val = vw1[o*6 + c];
        }
        pk.h[j] = (f16)(val * scsL[row]);
      }
    } else if (t < 24) {                            // c2
      const int tt = t-16, rt = tt >> 1, s = tt & 1, row = 16*rt + r15;
#pragma unroll
      for (int j = 0; j < 8; ++j) { const int k = 32*s + 8*g4 + j;
        pk.h[j] = (f16)(cw2[row*64 + k] * scsL[256+row]); }
    } else if (t < 32) {                            // v2 (x 1/3)
      const int tt = t-24, rt = tt >> 1, s = tt & 1, row = 16*rt + r15;
#pragma unroll
      for (int j = 0; j < 8; ++j) { const int k = 32*s + 8*g4 + j;
        pk.h[j] = (f16)(vw2[row*64 + k] * scsL[320+row]); }
    } else {                                        // s (64x128)
      const int tt = t-32, rt = tt >> 2, s = tt & 3, row = 16*rt + r15;
#pragma unroll
      for (int j = 0; j < 8; ++j) { const int k = 32*s + 8*g4 + j;
        pk.h[j] = (f16)(sw[row*128 + k] * scsL[384+row]); }
    }
    *(uint4*)(wsW + (size_t)t*512 + l*8) = pk.u;
  }
}

// ---------------- main: column-ownership, ONE barrier ----------------
// 8 waves x 32 cols each; all weights in LDS; per-wave activation buffers.
// After the single __syncthreads, all dependencies are intra-wave (DS ops
// from one wave execute in order -> read-then-overwrite of Hb is safe).
__global__ __launch_bounds__(512, 2) void sd_main(const int* __restrict__ faces,
    const float* __restrict__ verts, const float* __restrict__ centers,
    const f16* __restrict__ wsW, const float* __restrict__ shsG,
    float* __restrict__ out)
{
  __shared__ f16 Wl[24576];         // 48 KB weights, flat copy (fragment order)
  __shared__ f16 Hb[8][32][136];    // per-wave activations: k 0..127 (+8 pad)
  __shared__ f16 Xb[8][32][40];     // per-wave X: k 0..31 (+8 pad)
  __shared__ float shsL[448];

  const int tid  = threadIdx.x;
  const int lane = tid & 63;
  const int r15  = lane & 15;
  const int g4   = lane >> 4;
  const int w    = __builtin_amdgcn_readfirstlane(tid >> 6);
  const int by   = blockIdx.y;
  const int col0 = blockIdx.x * NT;

  // ---- stage weights (once per block) + shs ----
  {
    const uint4* src = (const uint4*)wsW;
    uint4* dst = (uint4*)Wl;
#pragma unroll
    for (int i = 0; i < 6; ++i) dst[tid + i*512] = src[tid + i*512];
  }
  if (tid < 448) shsL[tid] = shsG[tid];

  // ---- gather: 2 threads per column ----
  {
    const int col = tid >> 1, p = tid & 1;
    const int wg = col >> 5, cl = col & 31;
    const int f = col0 + col;
    const bool valid = f < FN_;
    const size_t fb3 = ((size_t)by*FN_ + (size_t)(valid ? f : 0)) * 3;
    f16* xrow = &Xb[wg][cl][0];
    if (p == 0) {
      const int i0 = faces[fb3 + 0], i1 = faces[fb3 + 1];
      const float* q0 = verts + ((size_t)by*V_ + (size_t)i0)*3;
      const float* q1 = verts + ((size_t)by*V_ + (size_t)i1)*3;
      float v0=0.f,v1=0.f,v2=0.f,v3=0.f,v4=0.f,v5=0.f;
      if (valid) { v0=q0[0]; v1=q0[1]; v2=q0[2]; v3=q1[0]; v4=q1[1]; v5=q1[2]; }
      Pk2 a,b,c;
      a.h[0]=(f16)v0; a.h[1]=(f16)v1; b.h[0]=(f16)v2; b.h[1]=(f16)v3;
      c.h[0]=(f16)v4; c.h[1]=(f16)v5;
      *(uint32_t*)&xrow[0] = a.u; *(uint32_t*)&xrow[2] = b.u; *(uint32_t*)&xrow[4] = c.u;
#pragma unroll
      for (int z = 0; z < 5; ++z) *(uint32_t*)&xrow[12 + 2*z] = 0u;   // k 12..21
    } else {
      const int i2 = faces[fb3 + 2];
      const float* q2 = verts + ((size_t)by*V_ + (size_t)i2)*3;
      float v0=0.f,v1=0.f,v2=0.f,v3=0.f,v4=0.f,v5=0.f;
      if (valid) { v0=q2[0]; v1=q2[1]; v2=q2[2];
                   v3=centers[((size_t)by*3+0)*FN_ + f];
                   v4=centers[((size_t)by*3+1)*FN_ + f];
                   v5=centers[((size_t)by*3+2)*FN_ + f]; }
      Pk2 a,b,c;
      a.h[0]=(f16)v0; a.h[1]=(f16)v1; b.h[0]=(f16)v2; b.h[1]=(f16)v3;
      c.h[0]=(f16)v4; c.h[1]=(f16)v5;
      *(uint32_t*)&xrow[6] = a.u; *(uint32_t*)&xrow[8] = b.u; *(uint32_t*)&xrow[10] = c.u;
#pragma unroll
      for (int z = 0; z < 5; ++z) *(uint32_t*)&xrow[22 + 2*z] = 0u;   // k 22..31
    }
  }
  __syncthreads();   // the ONLY barrier

  // ---- X fragments (held in regs for all of L1) ----
  const f16x8 bx0 = *(const f16x8*)&Xb[w][r15][8*g4];
  const f16x8 bx1 = *(const f16x8*)&Xb[w][16 + r15][8*g4];

  float cf[4][2][4], vf[4][2][4];

#pragma unroll
  for (int h = 0; h < 2; ++h) {
    // ---- L1 half h: weight tiles 8h..8h+7 -> Hb k0..127 ----
    //  h=0: c1 acts -> k0..63, e0 -> k64..127 ; h=1: e1 -> k0..63, e2 -> k64..127
#pragma unroll
    for (int t = 0; t < 8; ++t) {
      const int tg = 8*h + t;
      const f16x8 a = *(const f16x8*)&Wl[tg*512 + lane*8];
      const f32x4 shv = *(const f32x4*)&shsL[tg*16 + 4*g4];
      f32x4 a0 = __builtin_amdgcn_mfma_f32_16x16x32_f16(a, bx0, shv, 0,0,0);
      f32x4 a1 = __builtin_amdgcn_mfma_f32_16x16x32_f16(a, bx1, shv, 0,0,0);
      Pk4 p0, p1;
#pragma unroll
      for (int j = 0; j < 4; ++j) {
        p0.h[j] = (f16)fmaxf(a0[j], 0.f);
        p1.h[j] = (f16)fmaxf(a1[j], 0.f);
      }
      *(uint2*)&Hb[w][r15][t*16 + 4*g4]      = p0.u;
      *(uint2*)&Hb[w][16 + r15][t*16 + 4*g4] = p1.u;
    }

    // ---- L2 half h: sub=0 reads k0..63, sub=1 reads k64..127 ----
    //  h=0: sub0 = c2 -> cf ; sub1 = v2(e0) -> vf   h=1: v2(e1), v2(e2) -> vf+=
#pragma unroll
    for (int sub = 0; sub < 2; ++sub) {
      const bool is_c = (h == 0 && sub == 0);
      const int wbase = is_c ? 16 : 24;
      const int shb   = is_c ? 256 : 320;
      f16x8 Bf[2][2];
#pragma unroll
      for (int cg = 0; cg < 2; ++cg)
#pragma unroll
        for (int s = 0; s < 2; ++s)
          Bf[cg][s] = *(const f16x8*)&Hb[w][16*cg + r15][64*sub + 32*s + 8*g4];
#pragma unroll
      for (int rt = 0; rt < 4; ++rt) {
        const f16x8 a0 = *(const f16x8*)&Wl[(wbase + 2*rt + 0)*512 + lane*8];
        const f16x8 a1 = *(const f16x8*)&Wl[(wbase + 2*rt + 1)*512 + lane*8];
        const f32x4 shv = *(const f32x4*)&shsL[shb + rt*16 + 4*g4];
#pragma unroll
        for (int cg = 0; cg < 2; ++cg) {
          f32x4 acc = __builtin_amdgcn_mfma_f32_16x16x32_f16(a0, Bf[cg][0], shv, 0,0,0);
          acc = __builtin_amdgcn_mfma_f32_16x16x32_f16(a1, Bf[cg][1], acc, 0,0,0);
#pragma unroll
          for (int j = 0; j < 4; ++j) {
            const float val = fmaxf(acc[j], 0.f);
            if (h == 0) { if (sub == 0) cf[rt][cg][j] = val; else vf[rt][cg][j] = val; }
            else        vf[rt][cg][j] += val;
          }
        }
      }
    }
  }

  // ---- cv: cfeat -> Hb k0..63, vfeat -> k64..127 (overwrite; in-order DS) ----
#pragma unroll
  for (int rt = 0; rt < 4; ++rt)
#pragma unroll
    for (int cg = 0; cg < 2; ++cg) {
      Pk4 pc, pv;
#pragma unroll
      for (int j = 0; j < 4; ++j) {
        pc.h[j] = (f16)cf[rt][cg][j];
        pv.h[j] = (f16)vf[rt][cg][j];
      }
      *(uint2*)&Hb[w][16*cg + r15][rt*16 + 4*g4]      = pc.u;
      *(uint2*)&Hb[w][16*cg + r15][64 + rt*16 + 4*g4] = pv.u;
    }

  // ---- L3: Ws[64x128] x cv -> out ----
  {
    f32x4 acc[4][2];
#pragma unroll
    for (int rt = 0; rt < 4; ++rt) {
      const f32x4 shv = *(const f32x4*)&shsL[384 + rt*16 + 4*g4];
      acc[rt][0] = shv; acc[rt][1] = shv;
    }
#pragma unroll
    for (int s = 0; s < 4; ++s) {
      const f16x8 b0 = *(const f16x8*)&Hb[w][r15][32*s + 8*g4];
      const f16x8 b1 = *(const f16x8*)&Hb[w][16 + r15][32*s + 8*g4];
#pragma unroll
      for (int rt = 0; rt < 4; ++rt) {
        const f16x8 a = *(const f16x8*)&Wl[(32 + rt*4 + s)*512 + lane*8];
        acc[rt][0] = __builtin_amdgcn_mfma_f32_16x16x32_f16(a, b0, acc[rt][0], 0,0,0);
        acc[rt][1] = __builtin_amdgcn_mfma_f32_16x16x32_f16(a, b1, acc[rt][1], 0,0,0);
      }
    }
    const int fbase = col0 + 32*w + r15;
#pragma unroll
    for (int cg = 0; cg < 2; ++cg) {
      const int f = fbase + 16*cg;
      if (f < FN_) {
#pragma unroll
        for (int rt = 0; rt < 4; ++rt) {
          const size_t base = ((size_t)(by*64 + rt*16 + 4*g4))*FN_ + (size_t)f;
#pragma unroll
          for (int j = 0; j < 4; ++j)
            out[base + (size_t)j*FN_] = fmaxf(acc[rt][cg][j], 0.f);
        }
      }
    }
  }
}

extern "C" void kernel_launch(void* const* d_in, const int* in_sizes, int n_in,
                              void* d_out, int out_size, void* d_ws, size_t ws_size,
                              hipStream_t stream) {
  (void)in_sizes; (void)n_in; (void)out_size; (void)ws_size;
  Ptrs p;
  for (int i = 0; i < 33; ++i) p.p[i] = d_in[i];
  f16*   wsW  = (f16*)d_ws;
  float* shsG = (float*)((char*)d_ws + WS_SHS);
  hipLaunchKernelGGL(sd_prep, dim3(1), dim3(1024), 0, stream, p, wsW, shsG);
  hipLaunchKernelGGL(sd_main, dim3(NBX, B_), dim3(512), 0, stream,
                     (const int*)d_in[2], (const float*)d_in[1], (const float*)d_in[0],
                     wsW, shsG, (float*)d_out);
}

// Round 7
// 100.474 us; speedup vs baseline: 1.2537x; 1.2537x over previous
//
#include <hip/hip_runtime.h>
#include <cstddef>
#include <cstdint>

#define FN_ 100000
#define V_  50000
#define B_  8
#define NT  64
#define NBX ((FN_ + NT - 1) / NT)   // 1563; last block: 32 valid cols

// d_ws layout (bytes): 48 weight tiles of 1 KB (fragment order), then shs f32[448]
//   tiles  0..15 : combined L1 weights (256x32): rows 0-63 c1, 64-127 e0, 128-191 e1, 192-255 e2
//   tiles 16..23 : c2 (64x64)   tile = 16 + 2*rt + s
//   tiles 24..31 : v2 (64x64, x1/3 folded)  tile = 24 + 2*rt + s
//   tiles 32..47 : s  (64x128)  tile = 32 + 4*rt + s
#define WS_SHS 49152

typedef _Float16 f16;
typedef f16   f16x8 __attribute__((ext_vector_type(8)));
typedef float f32x4 __attribute__((ext_vector_type(4)));

struct Ptrs { const void* p[33]; };

union Pk8 { f16 h[8]; uint4 u; };

// 2x f32 -> packed f16 (RTZ), as raw u32 (avoids __fp16/_Float16 vec type clash)
__device__ __forceinline__ uint32_t pack2(float a, float b) {
  return __builtin_bit_cast(uint32_t, __builtin_amdgcn_cvt_pkrtz(a, b));
}
// packed relu on a u32 holding 2 f16: v_pk_max_f16 vs 0
__device__ __forceinline__ uint32_t pack_relu2(float a, float b) {
  uint32_t r, x = pack2(a, b);
  asm("v_pk_max_f16 %0, %1, 0" : "=v"(r) : "v"(x));
  return r;
}

// ---------------- prep: fold BN into f16 weights, fragment-ordered (validated) ----------------
__global__ __launch_bounds__(1024) void sd_prep(Ptrs in, f16* __restrict__ wsW,
                                                float* __restrict__ shsG)
{
  const float* __restrict__ cw1 = (const float*)in.p[3];
  const float* __restrict__ cb1 = (const float*)in.p[4];
  const float* __restrict__ c1g = (const float*)in.p[5];
  const float* __restrict__ c1bt= (const float*)in.p[6];
  const float* __restrict__ c1m = (const float*)in.p[7];
  const float* __restrict__ c1v = (const float*)in.p[8];
  const float* __restrict__ cw2 = (const float*)in.p[9];
  const float* __restrict__ cb2 = (const float*)in.p[10];
  const float* __restrict__ c2g = (const float*)in.p[11];
  const float* __restrict__ c2bt= (const float*)in.p[12];
  const float* __restrict__ c2m = (const float*)in.p[13];
  const float* __restrict__ c2v = (const float*)in.p[14];
  const float* __restrict__ vw1 = (const float*)in.p[15];
  const float* __restrict__ vb1 = (const float*)in.p[16];
  const float* __restrict__ v1g = (const float*)in.p[17];
  const float* __restrict__ v1bt= (const float*)in.p[18];
  const float* __restrict__ v1m = (const float*)in.p[19];
  const float* __restrict__ v1v = (const float*)in.p[20];
  const float* __restrict__ vw2 = (const float*)in.p[21];
  const float* __restrict__ vb2 = (const float*)in.p[22];
  const float* __restrict__ v2g = (const float*)in.p[23];
  const float* __restrict__ v2bt= (const float*)in.p[24];
  const float* __restrict__ v2m = (const float*)in.p[25];
  const float* __restrict__ v2v = (const float*)in.p[26];
  const float* __restrict__ sw  = (const float*)in.p[27];
  const float* __restrict__ sb  = (const float*)in.p[28];
  const float* __restrict__ s1g = (const float*)in.p[29];
  const float* __restrict__ s1bt= (const float*)in.p[30];
  const float* __restrict__ s1m = (const float*)in.p[31];
  const float* __restrict__ s1v = (const float*)in.p[32];

  __shared__ float scsL[448];
  const int tid = threadIdx.x;

  if (tid < 448) {
    const float *g, *v, *bb, *m, *bt; int o; float mul = 1.f;
    if (tid < 64)       { o = tid;      g=c1g; v=c1v; bb=cb1; m=c1m; bt=c1bt; }
    else if (tid < 256) { o = tid & 63; g=v1g; v=v1v; bb=vb1; m=v1m; bt=v1bt; }
    else if (tid < 320) { o = tid-256;  g=c2g; v=c2v; bb=cb2; m=c2m; bt=c2bt; }
    else if (tid < 384) { o = tid-320;  g=v2g; v=v2v; bb=vb2; m=v2m; bt=v2bt; mul = 1.f/3.f; }
    else                { o = tid-384;  g=s1g; v=s1v; bb=sb;  m=s1m; bt=s1bt; }
    float s = g[o] * rsqrtf(v[o] + 1e-5f);
    scsL[tid] = s * mul;
    shsG[tid] = ((bb[o] - m[o]) * s + bt[o]) * mul;
  }
  __syncthreads();

  for (int u = tid; u < 3072; u += 1024) {
    const int t = u >> 6, l = u & 63, r15 = l & 15, g4 = l >> 4;
    Pk8 pk;
    if (t < 16) {                                   // L1 combined 256x32
      const int wm = t >> 2, tr = t & 3, row = 64*wm + 16*tr + r15;
#pragma unroll
      for (int j = 0; j < 8; ++j) {
        const int k = 8*g4 + j; float val = 0.f;
        if (wm == 0) { if (k >= 9 && k < 12) val = cw1[row*3 + (k-9)]; }
        else if (k < 9) {
          const int e = wm - 1, o = row - 64*wm, c = (k - 3*e + 9) % 9;
          if (c < 6) val = vw1[o*6 + c];
        }
        pk.h[j] = (f16)(val * scsL[row]);
      }
    } else if (t < 24) {                            // c2
      const int tt = t-16, rt = tt >> 1, s = tt & 1, row = 16*rt + r15;
#pragma unroll
      for (int j = 0; j < 8; ++j) { const int k = 32*s + 8*g4 + j;
        pk.h[j] = (f16)(cw2[row*64 + k] * scsL[256+row]); }
    } else if (t < 32) {                            // v2 (x 1/3)
      const int tt = t-24, rt = tt >> 1, s = tt & 1, row = 16*rt + r15;
#pragma unroll
      for (int j = 0; j < 8; ++j) { const int k = 32*s + 8*g4 + j;
        pk.h[j] = (f16)(vw2[row*64 + k] * scsL[320+row]); }
    } else {                                        // s (64x128)
      const int tt = t-32, rt = tt >> 2, s = tt & 3, row = 16*rt + r15;
#pragma unroll
      for (int j = 0; j < 8; ++j) { const int k = 32*s + 8*g4 + j;
        pk.h[j] = (f16)(sw[row*128 + k] * scsL[384+row]); }
    }
    *(uint4*)(wsW + (size_t)t*512 + l*8) = pk.u;
  }
}

// ---------------- main: R3 phase structure, NT=64, 4 blocks/CU ----------------
// Phases: gather |1| L1(all 256 rows) |2| L2(4 branches) |3| cv |4| L3 -> store
__global__ __launch_bounds__(512, 8) void sd_main(const int* __restrict__ faces,
    const float* __restrict__ verts, const float* __restrict__ centers,
    const f16* __restrict__ wsW, const float* __restrict__ shsG,
    float* __restrict__ out)
{
  // Hs[col][k]: k 0..255 L1 acts (later 0..127 cv), 256..287 X, 288..295 pad
  // 39.7 KB total incl. shsL -> 4 blocks/CU at VGPR<=64
  __shared__ f16 Hs[NT][296];
  __shared__ float shsL[448];

  const int tid  = threadIdx.x;
  const int lane = tid & 63;
  const int r15  = lane & 15;
  const int g4   = lane >> 4;
  const int w    = __builtin_amdgcn_readfirstlane(tid >> 6);
  const int by   = blockIdx.y;
  const int col0 = blockIdx.x * NT;

  if (tid < 448) shsL[tid] = shsG[tid];

  // ---- gather: 8 threads per column ----
  {
    const int col = tid >> 3, p = tid & 7;
    const int f = col0 + col;
    const bool valid = f < FN_;
    if (p < 3) {
      float x0 = 0.f, x1 = 0.f, x2 = 0.f;
      if (valid) {
        const int vi = faces[((size_t)by*FN_ + f)*3 + p];
        const float* vp = verts + ((size_t)by*V_ + (size_t)vi)*3;
        x0 = vp[0]; x1 = vp[1]; x2 = vp[2];
      }
      Hs[col][256 + p*3 + 0] = (f16)x0;
      Hs[col][256 + p*3 + 1] = (f16)x1;
      Hs[col][256 + p*3 + 2] = (f16)x2;
    } else if (p == 3) {
#pragma unroll
      for (int k = 0; k < 3; ++k)
        Hs[col][265 + k] = valid ? (f16)centers[((size_t)by*3 + k)*FN_ + f] : (f16)0.f;
    } else {
#pragma unroll
      for (int z = 0; z < 5; ++z) Hs[col][268 + (p-4)*5 + z] = (f16)0.f;
    }
  }
  __syncthreads();

  const f16* __restrict__ wfrag = wsW + lane*8;   // per-lane weight-fragment base

  // ---- L1: W1[256x32] x X[32x64]; wave w owns row-tiles 2w, 2w+1 ----
  {
    const int t0 = 2*w, t1 = 2*w + 1;
    const f16x8 a0 = *(const f16x8*)(wfrag + (size_t)t0*512);
    const f16x8 a1 = *(const f16x8*)(wfrag + (size_t)t1*512);
    const f32x4 sh0 = *(const f32x4*)&shsL[t0*16 + 4*g4];
    const f32x4 sh1 = *(const f32x4*)&shsL[t1*16 + 4*g4];
#pragma unroll
    for (int tc = 0; tc < 4; ++tc) {
      const f16x8 b = *(const f16x8*)&Hs[16*tc + r15][256 + 8*g4];
      f32x4 c0 = __builtin_amdgcn_mfma_f32_16x16x32_f16(a0, b, sh0, 0,0,0);
      f32x4 c1 = __builtin_amdgcn_mfma_f32_16x16x32_f16(a1, b, sh1, 0,0,0);
      uint2 p0, p1;
      p0.x = pack_relu2(c0[0], c0[1]); p0.y = pack_relu2(c0[2], c0[3]);
      p1.x = pack_relu2(c1[0], c1[1]); p1.y = pack_relu2(c1[2], c1[3]);
      *(uint2*)&Hs[16*tc + r15][t0*16 + 4*g4] = p0;
      *(uint2*)&Hs[16*tc + r15][t1*16 + 4*g4] = p1;
    }
  }
  __syncthreads();

  const int rt = w & 3, cg = w >> 2;   // L2/L3 position: rows 16rt.., cols 32cg..
  float cf[2][4], vf[2][4];

  // ---- L2: 4 branches (c2, v2 x3), K=64 each ----
#pragma unroll
  for (int br = 0; br < 4; ++br) {
    const int wbase = br ? 24 : 16;
    const f16x8 a0 = *(const f16x8*)(wfrag + (size_t)(wbase + 2*rt + 0)*512);
    const f16x8 a1 = *(const f16x8*)(wfrag + (size_t)(wbase + 2*rt + 1)*512);
    const f32x4 shv = *(const f32x4*)&shsL[(br ? 320 : 256) + rt*16 + 4*g4];
#pragma unroll
    for (int tc = 0; tc < 2; ++tc) {
      const int col = 16*(2*cg + tc) + r15;
      const f16x8 b0 = *(const f16x8*)&Hs[col][64*br + 8*g4];
      const f16x8 b1 = *(const f16x8*)&Hs[col][64*br + 32 + 8*g4];
      f32x4 acc = __builtin_amdgcn_mfma_f32_16x16x32_f16(a0, b0, shv, 0,0,0);
      acc = __builtin_amdgcn_mfma_f32_16x16x32_f16(a1, b1, acc, 0,0,0);
#pragma unroll
      for (int j = 0; j < 4; ++j) {
        const float val = fmaxf(acc[j], 0.f);
        if (br == 0)      cf[tc][j]  = val;
        else if (br == 1) vf[tc][j]  = val;
        else              vf[tc][j] += val;
      }
    }
  }
  __syncthreads();   // all Hs k0..255 reads done

  // ---- cv: cfeat -> k0..63, vfeat -> k64..127 (already relu'd) ----
#pragma unroll
  for (int tc = 0; tc < 2; ++tc) {
    const int col = 16*(2*cg + tc) + r15;
    const int o0  = rt*16 + 4*g4;
    uint2 pc, pv;
    pc.x = pack2(cf[tc][0], cf[tc][1]); pc.y = pack2(cf[tc][2], cf[tc][3]);
    pv.x = pack2(vf[tc][0], vf[tc][1]); pv.y = pack2(vf[tc][2], vf[tc][3]);
    *(uint2*)&Hs[col][o0]      = pc;
    *(uint2*)&Hs[col][64 + o0] = pv;
  }
  __syncthreads();

  // ---- L3: Ws[64x128] x cv[128x64] -> out ----
  {
    const f32x4 shv = *(const f32x4*)&shsL[384 + rt*16 + 4*g4];
    f32x4 acc[2];
    acc[0] = shv; acc[1] = shv;
#pragma unroll
    for (int s = 0; s < 4; ++s) {
      const f16x8 a = *(const f16x8*)(wfrag + (size_t)(32 + rt*4 + s)*512);
#pragma unroll
      for (int tc = 0; tc < 2; ++tc) {
        const f16x8 b = *(const f16x8*)&Hs[16*(2*cg + tc) + r15][32*s + 8*g4];
        acc[tc] = __builtin_amdgcn_mfma_f32_16x16x32_f16(a, b, acc[tc], 0,0,0);
      }
    }
    const int o0 = rt*16 + 4*g4;
#pragma unroll
    for (int tc = 0; tc < 2; ++tc) {
      const int f = col0 + 16*(2*cg + tc) + r15;
      if (f < FN_) {
        const size_t base = ((size_t)(by*64 + o0))*FN_ + (size_t)f;
#pragma unroll
        for (int j = 0; j < 4; ++j)
          out[base + (size_t)j*FN_] = fmaxf(acc[tc][j], 0.f);
      }
    }
  }
}

extern "C" void kernel_launch(void* const* d_in, const int* in_sizes, int n_in,
                              void* d_out, int out_size, void* d_ws, size_t ws_size,
                              hipStream_t stream) {
  (void)in_sizes; (void)n_in; (void)out_size; (void)ws_size;
  Ptrs p;
  for (int i = 0; i < 33; ++i) p.p[i] = d_in[i];
  f16*   wsW  = (f16*)d_ws;
  float* shsG = (float*)((char*)d_ws + WS_SHS);
  hipLaunchKernelGGL(sd_prep, dim3(1), dim3(1024), 0, stream, p, wsW, shsG);
  hipLaunchKernelGGL(sd_main, dim3(NBX, B_), dim3(512), 0, stream,
                     (const int*)d_in[2], (const float*)d_in[1], (const float*)d_in[0],
                     wsW, shsG, (float*)d_out);
}